// Round 6
// baseline (268.788 us; speedup 1.0000x reference)
//
#include <hip/hip_runtime.h>

#define F_IN 128
#define HDIM 100
#define HPAD 128            // fp8 y1 row stride (bytes)
#define CDIM 16
#define CAP  64             // per-node slot capacity (Poisson(16): P(deg>=64)~2e-19)
#define BT_STRIDE 136       // LDS stride (bf16) for transposed W1
#define CHUNK 4096          // edges per P1 block
#define KMAX 200            // LDS bucket-counter array size (>= KBKT)
#define RCAP 64             // per-(bucket,chunk) run capacity (mean ~21)

static constexpr float LEAKY = 0.01f;

using short8  = __attribute__((ext_vector_type(8))) short;
using float4v = __attribute__((ext_vector_type(4))) float;
using float2v = __attribute__((ext_vector_type(2))) float;

__device__ __forceinline__ unsigned short f2bf(float f) {
    unsigned u = __float_as_uint(f);
    u += 0x7fffu + ((u >> 16) & 1u);     // round-to-nearest-even
    return (unsigned short)(u >> 16);
}

// ---------------- K1: fused Layer-1 GEMM (MFMA bf16 -> fp8) + CSR phase 1 ----------------

__global__ __launch_bounds__(256) void k_gemm1_p1(const float* __restrict__ x,
                                                  const float* __restrict__ W1,
                                                  unsigned char* __restrict__ y1f8,
                                                  const int* __restrict__ src,
                                                  const int* __restrict__ dst,
                                                  unsigned* __restrict__ bkt_edges,
                                                  int* __restrict__ cnt_arr,
                                                  int N, int E, int FB, int KBKT, int GB) {
    __shared__ union {
        unsigned short bt[F_IN * BT_STRIDE];                    // 34816 B (gemm role)
        struct { unsigned stage[CHUNK]; int cnt[KMAX]; } p1;    // 17184 B (fill role)
    } sm;
    int bx = blockIdx.x;
    int t = threadIdx.x;

    if (bx < FB) {
        // ---- P1 role ----
        unsigned* stage = sm.p1.stage;
        int* cnt = sm.p1.cnt;
        for (int i = t; i < KBKT; i += 256) cnt[i] = 0;
        __syncthreads();
        int e0 = bx * CHUNK, e1 = min(E, e0 + CHUNK);
        for (int i = e0 + t; i < e1; i += 256) {
            int d = dst[i];
            unsigned pk = ((unsigned)d << 16) | (unsigned)src[i];
            atomicAdd(&cnt[d >> 8], 1);
            stage[i - e0] = pk;
        }
        __syncthreads();
        for (int i = t; i < KBKT; i += 256) cnt_arr[bx * KBKT + i] = cnt[i];
        __syncthreads();
        for (int i = t; i < KBKT; i += 256) cnt[i] = 0;
        __syncthreads();
        int m = e1 - e0;
        for (int i = t; i < m; i += 256) {
            unsigned pk = stage[i];
            int b = pk >> 24;                       // dst >> 8
            int pos = atomicAdd(&cnt[b], 1);
            if (pos < RCAP)
                bkt_edges[((size_t)b * FB + bx) * RCAP + pos] = pk;
        }
        return;
    }

    // ---- gemm role ----
    for (int idx = t; idx < F_IN * HPAD; idx += 256) {
        int k = idx >> 7;          // 0..127
        int n = idx & 127;         // 0..127
        float v = (n < HDIM) ? W1[k * HDIM + n] : 0.f;
        sm.bt[n * BT_STRIDE + k] = f2bf(v);
    }
    __syncthreads();

    int wave = t >> 6, lane = t & 63;
    int Mtiles = (N + 15) >> 4;
    int m = lane & 15;
    int kq = lane >> 4;            // 0..3 quad

    for (int tile = (bx - FB) * 4 + wave; tile < Mtiles; tile += 4 * GB) {
        int row0 = tile * 16;
        int arow = min(row0 + m, N - 1);
        const float* xrow = x + (size_t)arow * F_IN;

        short8 afrag[4];
        #pragma unroll
        for (int kt = 0; kt < 4; ++kt) {
            int kb = kt * 32 + kq * 8;
            float4 a0 = *(const float4*)(xrow + kb);
            float4 a1 = *(const float4*)(xrow + kb + 4);
            short8 f;
            f[0] = (short)f2bf(a0.x); f[1] = (short)f2bf(a0.y);
            f[2] = (short)f2bf(a0.z); f[3] = (short)f2bf(a0.w);
            f[4] = (short)f2bf(a1.x); f[5] = (short)f2bf(a1.y);
            f[6] = (short)f2bf(a1.z); f[7] = (short)f2bf(a1.w);
            afrag[kt] = f;
        }

        bool full = (row0 + 15 < N);
        #pragma unroll
        for (int ct = 0; ct < 8; ++ct) {
            float4v acc = {0.f, 0.f, 0.f, 0.f};
            #pragma unroll
            for (int kt = 0; kt < 4; ++kt) {
                short8 b = *(const short8*)&sm.bt[(ct * 16 + m) * BT_STRIDE + kt * 32 + kq * 8];
                acc = __builtin_amdgcn_mfma_f32_16x16x32_bf16(afrag[kt], b, acc, 0, 0, 0);
            }
            // C layout: col = lane&15, row = (lane>>4)*4 + i
            #pragma unroll
            for (int i = 0; i < 4; ++i) {
                int r = row0 + kq * 4 + i;
                int v8 = __builtin_amdgcn_cvt_pk_fp8_f32(acc[i], acc[i], 0, false);
                if (full || r < N)
                    y1f8[(size_t)r * HPAD + ct * 16 + m] = (unsigned char)(v8 & 0xff);
            }
        }
    }
}

// ---------------- K2: CSR phase 2 ----------------

__global__ __launch_bounds__(256) void k_p2(const unsigned* __restrict__ bkt_edges,
                                            const int* __restrict__ cnt_arr,
                                            int* __restrict__ deg,
                                            unsigned short* __restrict__ slots,
                                            int N, int FB, int KBKT) {
    __shared__ int cur[256];
    int b = blockIdx.x, t = threadIdx.x;
    cur[t] = 0;
    __syncthreads();
    for (int fb = t; fb < FB; fb += 256) {
        int c = cnt_arr[fb * KBKT + b];
        size_t base = ((size_t)b * FB + fb) * RCAP;
        for (int j = 0; j < c; ++j) {
            unsigned pk = bkt_edges[base + j];
            int d = pk >> 16;
            int pos = atomicAdd(&cur[d & 255], 1);
            if (pos < CAP)
                slots[(size_t)d * CAP + pos] = (unsigned short)(pk & 0xffffu);
        }
    }
    __syncthreads();
    int n = (b << 8) + t;
    if (n < N) deg[n] = cur[t];
}

// ---------------- Layer 1 aggregation (+bias+leaky) fused with GEMM2 ----------------

__global__ __launch_bounds__(256) void k_agg1y2(const unsigned* __restrict__ y1u,
                                                const float* __restrict__ b1,
                                                const float* __restrict__ W2,
                                                const int* __restrict__ deg,
                                                const unsigned short* __restrict__ slots,
                                                float* __restrict__ y2, int N) {
    __shared__ float W2s[HDIM * CDIM];      // 6.25 KB, natural layout
    __shared__ float hs[4][2][HPAD];        // 4 KB
    int t = threadIdx.x;
    for (int idx = t; idx < HDIM * CDIM; idx += 256) W2s[idx] = W2[idx];
    __syncthreads();

    int wave = t >> 6, lane = t & 63;
    int half = lane >> 5, l = lane & 31;
    int hbase = lane & 32;                  // shfl index base for this half
    int n = blockIdx.x * 8 + wave * 2 + half;
    bool valid = (n < N);
    int nn = valid ? n : (N - 1);

    int beg = nn * CAP;
    int cnt = valid ? deg[nn] : 0;
    float dn = rsqrtf((float)deg[nn] + 1.0f);

    // wave-uniform loop bound = max(cnt over both halves)
    int cother = __shfl(cnt, lane ^ 32);
    int cmax = max(cnt, cother);

    float a0 = 0.f, a1 = 0.f, a2 = 0.f, a3 = 0.f;
    for (int e0 = 0; e0 < cmax; e0 += 32) {
        int mm = min(32, cnt - e0);         // may be <=0 for the smaller half
        unsigned su = 0u; float wv = 0.f;
        if (l < mm) {
            su = slots[beg + e0 + l];
            wv = rsqrtf((float)deg[su] + 1.0f);
        }
        int mmax = min(32, cmax - e0);
        int mpad = (mmax + 7) & ~7;
        for (int j = 0; j < mpad; j += 8) {
            float w[8]; unsigned vv[8];
            #pragma unroll
            for (int q = 0; q < 8; ++q) {
                int ln = hbase | (j + q);
                unsigned s = (unsigned)__shfl((int)su, ln);
                w[q] = __shfl(wv, ln);
                vv[q] = y1u[(size_t)s * 32 + l];
            }
            #pragma unroll
            for (int q = 0; q < 8; ++q) {
                float2v lov = __builtin_amdgcn_cvt_pk_f32_fp8((int)vv[q], false);
                float2v hiv = __builtin_amdgcn_cvt_pk_f32_fp8((int)vv[q], true);
                a0 = fmaf(w[q], lov[0], a0);
                a1 = fmaf(w[q], lov[1], a1);
                a2 = fmaf(w[q], hiv[0], a2);
                a3 = fmaf(w[q], hiv[1], a3);
            }
        }
    }
    // self-loop term (norm = dinv[n]^2; outer dn applied below)
    {
        unsigned vn = y1u[(size_t)nn * 32 + l];
        float2v lov = __builtin_amdgcn_cvt_pk_f32_fp8((int)vn, false);
        float2v hiv = __builtin_amdgcn_cvt_pk_f32_fp8((int)vn, true);
        a0 = fmaf(dn, lov[0], a0);
        a1 = fmaf(dn, lov[1], a1);
        a2 = fmaf(dn, hiv[0], a2);
        a3 = fmaf(dn, hiv[1], a3);
    }

    float4 bb = (l < 25) ? *(const float4*)&b1[4 * l] : make_float4(0.f, 0.f, 0.f, 0.f);
    float h0 = fmaf(dn, a0, bb.x);
    float h1 = fmaf(dn, a1, bb.y);
    float h2 = fmaf(dn, a2, bb.z);
    float h3 = fmaf(dn, a3, bb.w);
    h0 = h0 > 0.f ? h0 : LEAKY * h0;
    h1 = h1 > 0.f ? h1 : LEAKY * h1;
    h2 = h2 > 0.f ? h2 : LEAKY * h2;
    h3 = h3 > 0.f ? h3 : LEAKY * h3;
    *(float4*)&hs[wave][half][4 * l] = make_float4(h0, h1, h2, h3);
    __builtin_amdgcn_wave_barrier();

    // epilogue: y2[n,c] = sum_k h[k]*W2[k,c]; kg in {0,1}, k = 2j+kg
    int c = l & 15, kg = l >> 4;
    const float* hrow = hs[wave][half];
    float p = 0.f;
    #pragma unroll 10
    for (int j = 0; j < 50; ++j) {
        int k = 2 * j + kg;
        p = fmaf(hrow[k], W2s[k * CDIM + c], p);
    }
    p += __shfl_down(p, 16);
    if (l < 16 && valid) y2[(size_t)n * CDIM + c] = p;
}

// ---------------- Layer 2 aggregation + bias + log_softmax ----------------

__global__ __launch_bounds__(256) void k_agg2(const float* __restrict__ y2,
                                              const float* __restrict__ b2,
                                              const int* __restrict__ deg,
                                              const unsigned short* __restrict__ slots,
                                              float* __restrict__ out, int N) {
    int t = threadIdx.x;
    int wave = t >> 6, lane = t & 63;
    int sub = lane >> 4, c = lane & 15;
    int n = blockIdx.x * 16 + wave * 4 + sub;
    bool valid = (n < N);
    int nn = valid ? n : 0;

    int beg = nn * CAP;
    int cnt = valid ? deg[nn] : 0;
    float dn = rsqrtf((float)deg[nn] + 1.0f);
    float acc = dn * y2[(size_t)nn * CDIM + c];

    for (int e0 = 0; e0 < cnt; e0 += 16) {
        int mm = min(16, cnt - e0);
        unsigned su = 0u; float wv = 0.f;
        if (c < mm) {
            su = slots[beg + e0 + c];
            wv = rsqrtf((float)deg[su] + 1.0f);
        }
        int mpad = (mm + 3) & ~3;
        for (int j = 0; j < mpad; j += 4) {
            float w[4]; float v[4];
            #pragma unroll
            for (int q = 0; q < 4; ++q) {
                int ln = sub * 16 + j + q;
                unsigned s = (unsigned)__shfl((int)su, ln);
                w[q] = __shfl(wv, ln);
                v[q] = y2[(size_t)s * CDIM + c];
            }
            #pragma unroll
            for (int q = 0; q < 4; ++q) acc = fmaf(w[q], v[q], acc);
        }
    }

    float lg = fmaf(dn, acc, b2[c]);
    float mx = lg;
    #pragma unroll
    for (int k = 8; k; k >>= 1) mx = fmaxf(mx, __shfl_xor(mx, k));
    float ex = __expf(lg - mx);
    #pragma unroll
    for (int k = 8; k; k >>= 1) ex += __shfl_xor(ex, k);
    float lse = mx + __logf(ex);
    if (valid) out[(size_t)n * CDIM + c] = lg - lse;
}

// ---------------- launch ----------------

extern "C" void kernel_launch(void* const* d_in, const int* in_sizes, int n_in,
                              void* d_out, int out_size, void* d_ws, size_t ws_size,
                              hipStream_t stream) {
    const float* x  = (const float*)d_in[0];
    const float* W1 = (const float*)d_in[1];
    const float* b1 = (const float*)d_in[2];
    const float* W2 = (const float*)d_in[3];
    const float* b2 = (const float*)d_in[4];
    const int*   ei = (const int*)d_in[5];

    const int N = in_sizes[0] / F_IN;   // 50000
    const int E = in_sizes[5] / 2;      // 800000
    const int* src = ei;
    const int* dst = ei + E;

    const int KBKT = (N + 255) >> 8;    // 196 dst-buckets of 256 nodes
    const int FB   = (E + CHUNK - 1) / CHUNK;   // 196 P1 chunks

    char* ws = (char*)d_ws;
    size_t off = 0;
    auto alloc = [&](size_t bytes) {
        char* p = ws + off;
        off += (bytes + 255) & ~(size_t)255;
        return p;
    };
    int*            deg       = (int*)alloc((size_t)N * 4);
    unsigned char*  y1f8      = (unsigned char*)alloc((size_t)N * HPAD);
    float*          y2        = (float*)alloc((size_t)N * CDIM * 4);
    unsigned short* slots     = (unsigned short*)alloc((size_t)N * CAP * 2);
    int*            cnt_arr   = (int*)alloc((size_t)FB * KBKT * 4);
    unsigned*       bkt_edges = (unsigned*)alloc((size_t)KBKT * FB * RCAP * 4);
    (void)ws_size; (void)n_in; (void)out_size;

    const int GB = 262;

    // DECOMPOSITION ROUND: triplicate the three unmeasured kernels (all idempotent).
    // dur = 163.3 + 6*1.8 + 2*(p2_w + agg1y2_w + agg2_w)  ->  solves the warm sum;
    // replicas >=43 us additionally surface in rocprof top-5 with counters.
    k_gemm1_p1<<<FB + GB, 256, 0, stream>>>(x, W1, y1f8, src, dst,
                                            bkt_edges, cnt_arr, N, E, FB, KBKT, GB);
    k_p2<<<KBKT, 256, 0, stream>>>(bkt_edges, cnt_arr, deg, slots, N, FB, KBKT);
    k_p2<<<KBKT, 256, 0, stream>>>(bkt_edges, cnt_arr, deg, slots, N, FB, KBKT);
    k_p2<<<KBKT, 256, 0, stream>>>(bkt_edges, cnt_arr, deg, slots, N, FB, KBKT);
    k_agg1y2<<<(N + 7) / 8, 256, 0, stream>>>((const unsigned*)y1f8, b1, W2,
                                              deg, slots, y2, N);
    k_agg1y2<<<(N + 7) / 8, 256, 0, stream>>>((const unsigned*)y1f8, b1, W2,
                                              deg, slots, y2, N);
    k_agg1y2<<<(N + 7) / 8, 256, 0, stream>>>((const unsigned*)y1f8, b1, W2,
                                              deg, slots, y2, N);
    k_agg2<<<(N + 15) / 16, 256, 0, stream>>>(y2, b2, deg, slots,
                                              (float*)d_out, N);
    k_agg2<<<(N + 15) / 16, 256, 0, stream>>>(y2, b2, deg, slots,
                                              (float*)d_out, N);
    k_agg2<<<(N + 15) / 16, 256, 0, stream>>>(y2, b2, deg, slots,
                                              (float*)d_out, N);
}

// Round 7
// 161.442 us; speedup vs baseline: 1.6649x; 1.6649x over previous
//
#include <hip/hip_runtime.h>

#define F_IN 128
#define HDIM 100
#define HPAD 128            // fp8 y1 row stride (bytes)
#define CDIM 16
#define CAP  64             // per-node slot capacity (Poisson(16): P(deg>=64)~2e-19)
#define BT_STRIDE 136       // LDS stride (bf16) for transposed W1
#define CHUNK 4096          // edges per P1 block
#define KMAX 200            // LDS bucket-counter array size (>= KBKT)
#define RCAP 64             // per-(bucket,chunk) run capacity (mean ~21)

static constexpr float LEAKY = 0.01f;

using short8  = __attribute__((ext_vector_type(8))) short;
using float4v = __attribute__((ext_vector_type(4))) float;
using float2v = __attribute__((ext_vector_type(2))) float;

__device__ __forceinline__ unsigned short f2bf(float f) {
    unsigned u = __float_as_uint(f);
    u += 0x7fffu + ((u >> 16) & 1u);     // round-to-nearest-even
    return (unsigned short)(u >> 16);
}

__device__ __forceinline__ unsigned short f2h(float x) {
    union { unsigned short s; _Float16 f; } c;
    c.f = (_Float16)x;
    return c.s;
}

__device__ __forceinline__ float h2f(unsigned short u) {
    union { unsigned short s; _Float16 f; } c;
    c.s = u;
    return (float)c.f;
}

// ---------------- K1: fused Layer-1 GEMM (MFMA bf16 -> fp8) + CSR phase 1 ----------------

__global__ __launch_bounds__(256) void k_gemm1_p1(const float* __restrict__ x,
                                                  const float* __restrict__ W1,
                                                  unsigned char* __restrict__ y1f8,
                                                  const int* __restrict__ src,
                                                  const int* __restrict__ dst,
                                                  unsigned* __restrict__ bkt_edges,
                                                  int* __restrict__ cnt_arr,
                                                  int N, int E, int FB, int KBKT, int GB) {
    __shared__ union {
        unsigned short bt[F_IN * BT_STRIDE];                    // 34816 B (gemm role)
        struct { unsigned stage[CHUNK]; int cnt[KMAX]; } p1;    // 17184 B (fill role)
    } sm;
    int bx = blockIdx.x;
    int t = threadIdx.x;

    if (bx < FB) {
        // ---- P1 role ----
        unsigned* stage = sm.p1.stage;
        int* cnt = sm.p1.cnt;
        for (int i = t; i < KBKT; i += 256) cnt[i] = 0;
        __syncthreads();
        int e0 = bx * CHUNK, e1 = min(E, e0 + CHUNK);
        for (int i = e0 + t; i < e1; i += 256) {
            int d = dst[i];
            unsigned pk = ((unsigned)d << 16) | (unsigned)src[i];
            atomicAdd(&cnt[d >> 8], 1);
            stage[i - e0] = pk;
        }
        __syncthreads();
        for (int i = t; i < KBKT; i += 256) cnt_arr[bx * KBKT + i] = cnt[i];
        __syncthreads();
        for (int i = t; i < KBKT; i += 256) cnt[i] = 0;
        __syncthreads();
        int m = e1 - e0;
        for (int i = t; i < m; i += 256) {
            unsigned pk = stage[i];
            int b = pk >> 24;                       // dst >> 8
            int pos = atomicAdd(&cnt[b], 1);
            if (pos < RCAP)
                bkt_edges[((size_t)b * FB + bx) * RCAP + pos] = pk;
        }
        return;
    }

    // ---- gemm role ----
    for (int idx = t; idx < F_IN * HPAD; idx += 256) {
        int k = idx >> 7;          // 0..127
        int n = idx & 127;         // 0..127
        float v = (n < HDIM) ? W1[k * HDIM + n] : 0.f;
        sm.bt[n * BT_STRIDE + k] = f2bf(v);
    }
    __syncthreads();

    int wave = t >> 6, lane = t & 63;
    int Mtiles = (N + 15) >> 4;
    int m = lane & 15;
    int kq = lane >> 4;            // 0..3 quad

    for (int tile = (bx - FB) * 4 + wave; tile < Mtiles; tile += 4 * GB) {
        int row0 = tile * 16;
        int arow = min(row0 + m, N - 1);
        const float* xrow = x + (size_t)arow * F_IN;

        short8 afrag[4];
        #pragma unroll
        for (int kt = 0; kt < 4; ++kt) {
            int kb = kt * 32 + kq * 8;
            float4 a0 = *(const float4*)(xrow + kb);
            float4 a1 = *(const float4*)(xrow + kb + 4);
            short8 f;
            f[0] = (short)f2bf(a0.x); f[1] = (short)f2bf(a0.y);
            f[2] = (short)f2bf(a0.z); f[3] = (short)f2bf(a0.w);
            f[4] = (short)f2bf(a1.x); f[5] = (short)f2bf(a1.y);
            f[6] = (short)f2bf(a1.z); f[7] = (short)f2bf(a1.w);
            afrag[kt] = f;
        }

        bool full = (row0 + 15 < N);
        #pragma unroll
        for (int ct = 0; ct < 8; ++ct) {
            float4v acc = {0.f, 0.f, 0.f, 0.f};
            #pragma unroll
            for (int kt = 0; kt < 4; ++kt) {
                short8 b = *(const short8*)&sm.bt[(ct * 16 + m) * BT_STRIDE + kt * 32 + kq * 8];
                acc = __builtin_amdgcn_mfma_f32_16x16x32_bf16(afrag[kt], b, acc, 0, 0, 0);
            }
            // C layout: col = lane&15, row = (lane>>4)*4 + i
            #pragma unroll
            for (int i = 0; i < 4; ++i) {
                int r = row0 + kq * 4 + i;
                int v8 = __builtin_amdgcn_cvt_pk_fp8_f32(acc[i], acc[i], 0, false);
                if (full || r < N)
                    y1f8[(size_t)r * HPAD + ct * 16 + m] = (unsigned char)(v8 & 0xff);
            }
        }
    }
}

// ---------------- K2: CSR phase 2 — u32 slots {hi16: 0 (weight later), lo16: src} ------

__global__ __launch_bounds__(256) void k_p2(const unsigned* __restrict__ bkt_edges,
                                            const int* __restrict__ cnt_arr,
                                            int* __restrict__ deg,
                                            unsigned* __restrict__ slots,
                                            int N, int FB, int KBKT) {
    __shared__ int cur[256];
    int b = blockIdx.x, t = threadIdx.x;
    cur[t] = 0;
    __syncthreads();
    for (int fb = t; fb < FB; fb += 256) {
        int c = cnt_arr[fb * KBKT + b];
        size_t base = ((size_t)b * FB + fb) * RCAP;
        for (int j = 0; j < c; ++j) {
            unsigned pk = bkt_edges[base + j];
            int d = pk >> 16;
            int pos = atomicAdd(&cur[d & 255], 1);
            if (pos < CAP)
                slots[(size_t)d * CAP + pos] = pk & 0xffffu;
        }
    }
    __syncthreads();
    int n = (b << 8) + t;
    if (n < N) deg[n] = cur[t];
}

// ---------------- Layer 1 aggregation (+bias+leaky) fused with GEMM2 ----------------
// Gathers deg[su] per edge (as before) and ANNOTATES the slot with fp16(wv) so k_agg2
// gets index+weight in one load — eliminates agg2's per-edge deg-gather + rsqrt chain.

__global__ __launch_bounds__(256) void k_agg1y2(const unsigned* __restrict__ y1u,
                                                const float* __restrict__ b1,
                                                const float* __restrict__ W2,
                                                const int* __restrict__ deg,
                                                unsigned* __restrict__ slots,
                                                float* __restrict__ y2, int N) {
    __shared__ float W2s[HDIM * CDIM];      // 6.25 KB, natural layout
    __shared__ float hs[4][2][HPAD];        // 4 KB
    int t = threadIdx.x;
    for (int idx = t; idx < HDIM * CDIM; idx += 256) W2s[idx] = W2[idx];
    __syncthreads();

    int wave = t >> 6, lane = t & 63;
    int half = lane >> 5, l = lane & 31;
    int hbase = lane & 32;                  // shfl index base for this half
    int n = blockIdx.x * 8 + wave * 2 + half;
    bool valid = (n < N);
    int nn = valid ? n : (N - 1);

    int beg = nn * CAP;
    int cnt = valid ? deg[nn] : 0;
    float dn = rsqrtf((float)deg[nn] + 1.0f);

    // wave-uniform loop bound = max(cnt over both halves)
    int cother = __shfl(cnt, lane ^ 32);
    int cmax = max(cnt, cother);

    float a0 = 0.f, a1 = 0.f, a2 = 0.f, a3 = 0.f;
    for (int e0 = 0; e0 < cmax; e0 += 32) {
        int mm = min(32, cnt - e0);         // may be <=0 for the smaller half
        unsigned su = 0u; float wv = 0.f;
        if (l < mm) {
            su = slots[beg + e0 + l] & 0xffffu;
            wv = rsqrtf((float)deg[su] + 1.0f);
            slots[beg + e0 + l] = su | ((unsigned)f2h(wv) << 16);   // annotate for agg2
        }
        int mmax = min(32, cmax - e0);
        int mpad = (mmax + 7) & ~7;
        for (int j = 0; j < mpad; j += 8) {
            float w[8]; unsigned vv[8];
            #pragma unroll
            for (int q = 0; q < 8; ++q) {
                int ln = hbase | (j + q);
                unsigned s = (unsigned)__shfl((int)su, ln);
                w[q] = __shfl(wv, ln);
                vv[q] = y1u[(size_t)s * 32 + l];
            }
            #pragma unroll
            for (int q = 0; q < 8; ++q) {
                float2v lov = __builtin_amdgcn_cvt_pk_f32_fp8((int)vv[q], false);
                float2v hiv = __builtin_amdgcn_cvt_pk_f32_fp8((int)vv[q], true);
                a0 = fmaf(w[q], lov[0], a0);
                a1 = fmaf(w[q], lov[1], a1);
                a2 = fmaf(w[q], hiv[0], a2);
                a3 = fmaf(w[q], hiv[1], a3);
            }
        }
    }
    // self-loop term (norm = dinv[n]^2; outer dn applied below)
    {
        unsigned vn = y1u[(size_t)nn * 32 + l];
        float2v lov = __builtin_amdgcn_cvt_pk_f32_fp8((int)vn, false);
        float2v hiv = __builtin_amdgcn_cvt_pk_f32_fp8((int)vn, true);
        a0 = fmaf(dn, lov[0], a0);
        a1 = fmaf(dn, lov[1], a1);
        a2 = fmaf(dn, hiv[0], a2);
        a3 = fmaf(dn, hiv[1], a3);
    }

    float4 bb = (l < 25) ? *(const float4*)&b1[4 * l] : make_float4(0.f, 0.f, 0.f, 0.f);
    float h0 = fmaf(dn, a0, bb.x);
    float h1 = fmaf(dn, a1, bb.y);
    float h2 = fmaf(dn, a2, bb.z);
    float h3 = fmaf(dn, a3, bb.w);
    h0 = h0 > 0.f ? h0 : LEAKY * h0;
    h1 = h1 > 0.f ? h1 : LEAKY * h1;
    h2 = h2 > 0.f ? h2 : LEAKY * h2;
    h3 = h3 > 0.f ? h3 : LEAKY * h3;
    *(float4*)&hs[wave][half][4 * l] = make_float4(h0, h1, h2, h3);
    __builtin_amdgcn_wave_barrier();

    // epilogue: y2[n,c] = sum_k h[k]*W2[k,c]; kg in {0,1}, k = 2j+kg
    int c = l & 15, kg = l >> 4;
    const float* hrow = hs[wave][half];
    float p = 0.f;
    #pragma unroll 10
    for (int j = 0; j < 50; ++j) {
        int k = 2 * j + kg;
        p = fmaf(hrow[k], W2s[k * CDIM + c], p);
    }
    p += __shfl_down(p, 16);
    if (l < 16 && valid) y2[(size_t)n * CDIM + c] = p;
}

// ---------------- Layer 2 aggregation + bias + log_softmax ----------------
// Slot load now yields index AND fp16 weight — no deg gather, no rsqrt chain.

__global__ __launch_bounds__(256) void k_agg2(const float* __restrict__ y2,
                                              const float* __restrict__ b2,
                                              const int* __restrict__ deg,
                                              const unsigned* __restrict__ slots,
                                              float* __restrict__ out, int N) {
    int t = threadIdx.x;
    int wave = t >> 6, lane = t & 63;
    int sub = lane >> 4, c = lane & 15;
    int n = blockIdx.x * 16 + wave * 4 + sub;
    bool valid = (n < N);
    int nn = valid ? n : 0;

    int beg = nn * CAP;
    int cnt = valid ? deg[nn] : 0;
    float dn = rsqrtf((float)deg[nn] + 1.0f);
    float acc = dn * y2[(size_t)nn * CDIM + c];

    for (int e0 = 0; e0 < cnt; e0 += 16) {
        int mm = min(16, cnt - e0);
        unsigned su = 0u; float wv = 0.f;
        if (c < mm) {
            unsigned sv = slots[beg + e0 + c];
            su = sv & 0xffffu;
            wv = h2f((unsigned short)(sv >> 16));
        }
        int mpad = (mm + 3) & ~3;
        for (int j = 0; j < mpad; j += 4) {
            float w[4]; float v[4];
            #pragma unroll
            for (int q = 0; q < 4; ++q) {
                int ln = sub * 16 + j + q;
                unsigned s = (unsigned)__shfl((int)su, ln);
                w[q] = __shfl(wv, ln);
                v[q] = y2[(size_t)s * CDIM + c];
            }
            #pragma unroll
            for (int q = 0; q < 4; ++q) acc = fmaf(w[q], v[q], acc);
        }
    }

    float lg = fmaf(dn, acc, b2[c]);
    float mx = lg;
    #pragma unroll
    for (int k = 8; k; k >>= 1) mx = fmaxf(mx, __shfl_xor(mx, k));
    float ex = __expf(lg - mx);
    #pragma unroll
    for (int k = 8; k; k >>= 1) ex += __shfl_xor(ex, k);
    float lse = mx + __logf(ex);
    if (valid) out[(size_t)n * CDIM + c] = lg - lse;
}

// ---------------- launch ----------------

extern "C" void kernel_launch(void* const* d_in, const int* in_sizes, int n_in,
                              void* d_out, int out_size, void* d_ws, size_t ws_size,
                              hipStream_t stream) {
    const float* x  = (const float*)d_in[0];
    const float* W1 = (const float*)d_in[1];
    const float* b1 = (const float*)d_in[2];
    const float* W2 = (const float*)d_in[3];
    const float* b2 = (const float*)d_in[4];
    const int*   ei = (const int*)d_in[5];

    const int N = in_sizes[0] / F_IN;   // 50000
    const int E = in_sizes[5] / 2;      // 800000
    const int* src = ei;
    const int* dst = ei + E;

    const int KBKT = (N + 255) >> 8;    // 196 dst-buckets of 256 nodes
    const int FB   = (E + CHUNK - 1) / CHUNK;   // 196 P1 chunks

    char* ws = (char*)d_ws;
    size_t off = 0;
    auto alloc = [&](size_t bytes) {
        char* p = ws + off;
        off += (bytes + 255) & ~(size_t)255;
        return p;
    };
    int*            deg       = (int*)alloc((size_t)N * 4);
    unsigned char*  y1f8      = (unsigned char*)alloc((size_t)N * HPAD);
    float*          y2        = (float*)alloc((size_t)N * CDIM * 4);
    unsigned*       slots     = (unsigned*)alloc((size_t)N * CAP * 4);
    int*            cnt_arr   = (int*)alloc((size_t)FB * KBKT * 4);
    unsigned*       bkt_edges = (unsigned*)alloc((size_t)KBKT * FB * RCAP * 4);
    (void)ws_size; (void)n_in; (void)out_size;

    const int GB = 262;

    k_gemm1_p1<<<FB + GB, 256, 0, stream>>>(x, W1, y1f8, src, dst,
                                            bkt_edges, cnt_arr, N, E, FB, KBKT, GB);
    k_p2<<<KBKT, 256, 0, stream>>>(bkt_edges, cnt_arr, deg, slots, N, FB, KBKT);
    k_agg1y2<<<(N + 7) / 8, 256, 0, stream>>>((const unsigned*)y1f8, b1, W2,
                                              deg, slots, y2, N);
    k_agg2<<<(N + 15) / 16, 256, 0, stream>>>(y2, b2, deg, slots,
                                              (float*)d_out, N);
}

// Round 8
// 158.639 us; speedup vs baseline: 1.6943x; 1.0177x over previous
//
#include <hip/hip_runtime.h>

#define F_IN 128
#define HDIM 100
#define HPAD 128            // fp8 y1 row stride (bytes)
#define CDIM 16
#define CAP  64             // per-node slot capacity (Poisson(16): P(deg>=64)~2e-19)
#define BT_STRIDE 136       // LDS stride (bf16) for transposed W1
#define CHUNK 4096          // edges per P1 block
#define KMAX 200            // LDS bucket-counter array size (>= KBKT)
#define RCAP 64             // per-(bucket,chunk) run capacity (mean ~21)

static constexpr float LEAKY = 0.01f;

using short8  = __attribute__((ext_vector_type(8))) short;
using float4v = __attribute__((ext_vector_type(4))) float;
using float2v = __attribute__((ext_vector_type(2))) float;

__device__ __forceinline__ unsigned short f2bf(float f) {
    unsigned u = __float_as_uint(f);
    u += 0x7fffu + ((u >> 16) & 1u);     // round-to-nearest-even
    return (unsigned short)(u >> 16);
}

__device__ __forceinline__ unsigned short f2h(float x) {
    union { unsigned short s; _Float16 f; } c;
    c.f = (_Float16)x;
    return c.s;
}

__device__ __forceinline__ float h2f(unsigned short u) {
    union { unsigned short s; _Float16 f; } c;
    c.s = u;
    return (float)c.f;
}

// ---------------- K1: fused Layer-1 GEMM (MFMA bf16 -> fp8) + CSR phase 1 ----------------
// MLP round: staging/edge loops unrolled so 16 independent loads are in flight
// instead of 1 (the rolled W1-staging loop was ~1 serial load-latency per element).

__global__ __launch_bounds__(256) void k_gemm1_p1(const float* __restrict__ x,
                                                  const float* __restrict__ W1,
                                                  unsigned char* __restrict__ y1f8,
                                                  const int* __restrict__ src,
                                                  const int* __restrict__ dst,
                                                  unsigned* __restrict__ bkt_edges,
                                                  int* __restrict__ cnt_arr,
                                                  int N, int E, int FB, int KBKT, int GB) {
    __shared__ union {
        unsigned short bt[F_IN * BT_STRIDE];                    // 34816 B (gemm role)
        struct { unsigned stage[CHUNK]; int cnt[KMAX]; } p1;    // 17184 B (fill role)
    } sm;
    int bx = blockIdx.x;
    int t = threadIdx.x;

    if (bx < FB) {
        // ---- P1 role ----
        unsigned* stage = sm.p1.stage;
        int* cnt = sm.p1.cnt;
        for (int i = t; i < KBKT; i += 256) cnt[i] = 0;
        __syncthreads();
        int e0 = bx * CHUNK, e1 = min(E, e0 + CHUNK);
        #pragma unroll 4
        for (int i = e0 + t; i < e1; i += 256) {
            int d = dst[i];
            unsigned pk = ((unsigned)d << 16) | (unsigned)src[i];
            atomicAdd(&cnt[d >> 8], 1);
            stage[i - e0] = pk;
        }
        __syncthreads();
        for (int i = t; i < KBKT; i += 256) cnt_arr[bx * KBKT + i] = cnt[i];
        __syncthreads();
        for (int i = t; i < KBKT; i += 256) cnt[i] = 0;
        __syncthreads();
        int m = e1 - e0;
        #pragma unroll 4
        for (int i = t; i < m; i += 256) {
            unsigned pk = stage[i];
            int b = pk >> 24;                       // dst >> 8
            int pos = atomicAdd(&cnt[b], 1);
            if (pos < RCAP)
                bkt_edges[((size_t)b * FB + bx) * RCAP + pos] = pk;
        }
        return;
    }

    // ---- gemm role ----
    #pragma unroll 16
    for (int idx = t; idx < F_IN * HPAD; idx += 256) {
        int k = idx >> 7;          // 0..127
        int n = idx & 127;         // 0..127
        float v = (n < HDIM) ? W1[k * HDIM + n] : 0.f;
        sm.bt[n * BT_STRIDE + k] = f2bf(v);
    }
    __syncthreads();

    int wave = t >> 6, lane = t & 63;
    int Mtiles = (N + 15) >> 4;
    int m = lane & 15;
    int kq = lane >> 4;            // 0..3 quad

    for (int tile = (bx - FB) * 4 + wave; tile < Mtiles; tile += 4 * GB) {
        int row0 = tile * 16;
        int arow = min(row0 + m, N - 1);
        const float* xrow = x + (size_t)arow * F_IN;

        short8 afrag[4];
        #pragma unroll
        for (int kt = 0; kt < 4; ++kt) {
            int kb = kt * 32 + kq * 8;
            float4 a0 = *(const float4*)(xrow + kb);
            float4 a1 = *(const float4*)(xrow + kb + 4);
            short8 f;
            f[0] = (short)f2bf(a0.x); f[1] = (short)f2bf(a0.y);
            f[2] = (short)f2bf(a0.z); f[3] = (short)f2bf(a0.w);
            f[4] = (short)f2bf(a1.x); f[5] = (short)f2bf(a1.y);
            f[6] = (short)f2bf(a1.z); f[7] = (short)f2bf(a1.w);
            afrag[kt] = f;
        }

        bool full = (row0 + 15 < N);
        #pragma unroll
        for (int ct = 0; ct < 8; ++ct) {
            float4v acc = {0.f, 0.f, 0.f, 0.f};
            #pragma unroll
            for (int kt = 0; kt < 4; ++kt) {
                short8 b = *(const short8*)&sm.bt[(ct * 16 + m) * BT_STRIDE + kt * 32 + kq * 8];
                acc = __builtin_amdgcn_mfma_f32_16x16x32_bf16(afrag[kt], b, acc, 0, 0, 0);
            }
            // C layout: col = lane&15, row = (lane>>4)*4 + i
            #pragma unroll
            for (int i = 0; i < 4; ++i) {
                int r = row0 + kq * 4 + i;
                int v8 = __builtin_amdgcn_cvt_pk_fp8_f32(acc[i], acc[i], 0, false);
                if (full || r < N)
                    y1f8[(size_t)r * HPAD + ct * 16 + m] = (unsigned char)(v8 & 0xff);
            }
        }
    }
}

// ---------------- K2: CSR phase 2 — uint4 run reads (21 serial scalar -> ~6 vector) ----

__global__ __launch_bounds__(256) void k_p2(const unsigned* __restrict__ bkt_edges,
                                            const int* __restrict__ cnt_arr,
                                            int* __restrict__ deg,
                                            unsigned* __restrict__ slots,
                                            int N, int FB, int KBKT) {
    __shared__ int cur[256];
    int b = blockIdx.x, t = threadIdx.x;
    cur[t] = 0;
    __syncthreads();
    for (int fb = t; fb < FB; fb += 256) {
        int c = cnt_arr[fb * KBKT + b];
        size_t base = ((size_t)b * FB + fb) * RCAP;     // 256B-aligned (RCAP=64)
        int j = 0;
        for (; j + 3 < c; j += 4) {
            uint4 pk4 = *(const uint4*)&bkt_edges[base + j];
            unsigned pks[4] = {pk4.x, pk4.y, pk4.z, pk4.w};
            #pragma unroll
            for (int q = 0; q < 4; ++q) {
                unsigned pk = pks[q];
                int d = pk >> 16;
                int pos = atomicAdd(&cur[d & 255], 1);
                if (pos < CAP)
                    slots[(size_t)d * CAP + pos] = pk & 0xffffu;
            }
        }
        for (; j < c; ++j) {
            unsigned pk = bkt_edges[base + j];
            int d = pk >> 16;
            int pos = atomicAdd(&cur[d & 255], 1);
            if (pos < CAP)
                slots[(size_t)d * CAP + pos] = pk & 0xffffu;
        }
    }
    __syncthreads();
    int n = (b << 8) + t;
    if (n < N) deg[n] = cur[t];
}

// ---------------- Layer 1 aggregation (+bias+leaky) fused with GEMM2 ----------------
// Gather batch widened 8 -> 16 (16 row-gathers in flight); self-loop load + bias
// hoisted above the edge loop. Slot annotated with fp16(wv) for agg2.

__global__ __launch_bounds__(256) void k_agg1y2(const unsigned* __restrict__ y1u,
                                                const float* __restrict__ b1,
                                                const float* __restrict__ W2,
                                                const int* __restrict__ deg,
                                                unsigned* __restrict__ slots,
                                                float* __restrict__ y2, int N) {
    __shared__ float W2s[HDIM * CDIM];      // 6.25 KB, natural layout
    __shared__ float hs[4][2][HPAD];        // 4 KB
    int t = threadIdx.x;
    #pragma unroll 4
    for (int idx = t; idx < HDIM * CDIM; idx += 256) W2s[idx] = W2[idx];
    __syncthreads();

    int wave = t >> 6, lane = t & 63;
    int half = lane >> 5, l = lane & 31;
    int hbase = lane & 32;                  // shfl index base for this half
    int n = blockIdx.x * 8 + wave * 2 + half;
    bool valid = (n < N);
    int nn = valid ? n : (N - 1);

    int beg = nn * CAP;
    int cnt = valid ? deg[nn] : 0;
    float dn = rsqrtf((float)deg[nn] + 1.0f);

    // issue self-loop row + bias early (consumed after the edge loop)
    unsigned vn = y1u[(size_t)nn * 32 + l];
    float4 bb = (l < 25) ? *(const float4*)&b1[4 * l] : make_float4(0.f, 0.f, 0.f, 0.f);

    // wave-uniform loop bound = max(cnt over both halves)
    int cother = __shfl(cnt, lane ^ 32);
    int cmax = max(cnt, cother);

    float a0 = 0.f, a1 = 0.f, a2 = 0.f, a3 = 0.f;
    for (int e0 = 0; e0 < cmax; e0 += 32) {
        int mm = min(32, cnt - e0);         // may be <=0 for the smaller half
        unsigned su = 0u; float wv = 0.f;
        if (l < mm) {
            su = slots[beg + e0 + l] & 0xffffu;
            wv = rsqrtf((float)deg[su] + 1.0f);
            slots[beg + e0 + l] = su | ((unsigned)f2h(wv) << 16);   // annotate for agg2
        }
        int mmax = min(32, cmax - e0);
        int mpad = (mmax + 15) & ~15;
        for (int j = 0; j < mpad; j += 16) {
            float w[16]; unsigned vv[16];
            #pragma unroll
            for (int q = 0; q < 16; ++q) {
                int ln = hbase | (j + q);
                unsigned s = (unsigned)__shfl((int)su, ln);
                w[q] = __shfl(wv, ln);
                vv[q] = y1u[(size_t)s * 32 + l];
            }
            #pragma unroll
            for (int q = 0; q < 16; ++q) {
                float2v lov = __builtin_amdgcn_cvt_pk_f32_fp8((int)vv[q], false);
                float2v hiv = __builtin_amdgcn_cvt_pk_f32_fp8((int)vv[q], true);
                a0 = fmaf(w[q], lov[0], a0);
                a1 = fmaf(w[q], lov[1], a1);
                a2 = fmaf(w[q], hiv[0], a2);
                a3 = fmaf(w[q], hiv[1], a3);
            }
        }
    }
    // self-loop term (norm = dinv[n]^2; outer dn applied below)
    {
        float2v lov = __builtin_amdgcn_cvt_pk_f32_fp8((int)vn, false);
        float2v hiv = __builtin_amdgcn_cvt_pk_f32_fp8((int)vn, true);
        a0 = fmaf(dn, lov[0], a0);
        a1 = fmaf(dn, lov[1], a1);
        a2 = fmaf(dn, hiv[0], a2);
        a3 = fmaf(dn, hiv[1], a3);
    }

    float h0 = fmaf(dn, a0, bb.x);
    float h1 = fmaf(dn, a1, bb.y);
    float h2 = fmaf(dn, a2, bb.z);
    float h3 = fmaf(dn, a3, bb.w);
    h0 = h0 > 0.f ? h0 : LEAKY * h0;
    h1 = h1 > 0.f ? h1 : LEAKY * h1;
    h2 = h2 > 0.f ? h2 : LEAKY * h2;
    h3 = h3 > 0.f ? h3 : LEAKY * h3;
    *(float4*)&hs[wave][half][4 * l] = make_float4(h0, h1, h2, h3);
    __builtin_amdgcn_wave_barrier();

    // epilogue: y2[n,c] = sum_k h[k]*W2[k,c]; kg in {0,1}, k = 2j+kg
    int c = l & 15, kg = l >> 4;
    const float* hrow = hs[wave][half];
    float p = 0.f;
    #pragma unroll 10
    for (int j = 0; j < 50; ++j) {
        int k = 2 * j + kg;
        p = fmaf(hrow[k], W2s[k * CDIM + c], p);
    }
    p += __shfl_down(p, 16);
    if (l < 16 && valid) y2[(size_t)n * CDIM + c] = p;
}

// ---------------- Layer 2 aggregation + bias + log_softmax ----------------
// Slot load yields index AND fp16 weight; gather batch widened 4 -> 16.

__global__ __launch_bounds__(256) void k_agg2(const float* __restrict__ y2,
                                              const float* __restrict__ b2,
                                              const int* __restrict__ deg,
                                              const unsigned* __restrict__ slots,
                                              float* __restrict__ out, int N) {
    int t = threadIdx.x;
    int wave = t >> 6, lane = t & 63;
    int sub = lane >> 4, c = lane & 15;
    int n = blockIdx.x * 16 + wave * 4 + sub;
    bool valid = (n < N);
    int nn = valid ? n : 0;

    int beg = nn * CAP;
    int cnt = valid ? deg[nn] : 0;
    float dn = rsqrtf((float)deg[nn] + 1.0f);
    float acc = dn * y2[(size_t)nn * CDIM + c];

    for (int e0 = 0; e0 < cnt; e0 += 16) {
        int mm = min(16, cnt - e0);
        unsigned su = 0u; float wv = 0.f;
        if (c < mm) {
            unsigned sv = slots[beg + e0 + c];
            su = sv & 0xffffu;
            wv = h2f((unsigned short)(sv >> 16));
        }
        float w[16]; float v[16];
        #pragma unroll
        for (int q = 0; q < 16; ++q) {
            int ln = sub * 16 + q;
            unsigned s = (unsigned)__shfl((int)su, ln);
            w[q] = __shfl(wv, ln);
            v[q] = y2[(size_t)s * CDIM + c];
        }
        #pragma unroll
        for (int q = 0; q < 16; ++q) acc = fmaf(w[q], v[q], acc);
    }

    float lg = fmaf(dn, acc, b2[c]);
    float mx = lg;
    #pragma unroll
    for (int k = 8; k; k >>= 1) mx = fmaxf(mx, __shfl_xor(mx, k));
    float ex = __expf(lg - mx);
    #pragma unroll
    for (int k = 8; k; k >>= 1) ex += __shfl_xor(ex, k);
    float lse = mx + __logf(ex);
    if (valid) out[(size_t)n * CDIM + c] = lg - lse;
}

// ---------------- launch ----------------

extern "C" void kernel_launch(void* const* d_in, const int* in_sizes, int n_in,
                              void* d_out, int out_size, void* d_ws, size_t ws_size,
                              hipStream_t stream) {
    const float* x  = (const float*)d_in[0];
    const float* W1 = (const float*)d_in[1];
    const float* b1 = (const float*)d_in[2];
    const float* W2 = (const float*)d_in[3];
    const float* b2 = (const float*)d_in[4];
    const int*   ei = (const int*)d_in[5];

    const int N = in_sizes[0] / F_IN;   // 50000
    const int E = in_sizes[5] / 2;      // 800000
    const int* src = ei;
    const int* dst = ei + E;

    const int KBKT = (N + 255) >> 8;    // 196 dst-buckets of 256 nodes
    const int FB   = (E + CHUNK - 1) / CHUNK;   // 196 P1 chunks

    char* ws = (char*)d_ws;
    size_t off = 0;
    auto alloc = [&](size_t bytes) {
        char* p = ws + off;
        off += (bytes + 255) & ~(size_t)255;
        return p;
    };
    int*            deg       = (int*)alloc((size_t)N * 4);
    unsigned char*  y1f8      = (unsigned char*)alloc((size_t)N * HPAD);
    float*          y2        = (float*)alloc((size_t)N * CDIM * 4);
    unsigned*       slots     = (unsigned*)alloc((size_t)N * CAP * 4);
    int*            cnt_arr   = (int*)alloc((size_t)FB * KBKT * 4);
    unsigned*       bkt_edges = (unsigned*)alloc((size_t)KBKT * FB * RCAP * 4);
    (void)ws_size; (void)n_in; (void)out_size;

    const int GB = 262;

    k_gemm1_p1<<<FB + GB, 256, 0, stream>>>(x, W1, y1f8, src, dst,
                                            bkt_edges, cnt_arr, N, E, FB, KBKT, GB);
    k_p2<<<KBKT, 256, 0, stream>>>(bkt_edges, cnt_arr, deg, slots, N, FB, KBKT);
    k_agg1y2<<<(N + 7) / 8, 256, 0, stream>>>((const unsigned*)y1f8, b1, W2,
                                              deg, slots, y2, N);
    k_agg2<<<(N + 15) / 16, 256, 0, stream>>>(y2, b2, deg, slots,
                                              (float*)d_out, N);
}